// Round 3
// baseline (427.373 us; speedup 1.0000x reference)
//
#include <hip/hip_runtime.h>
#include <hip/hip_bf16.h>

#define S_LEN 1024
#define BATCH 2048
#define HID   64
#define GB    4               // batch rows per group
#define MB    8               // rows per block = 2 independent groups
#define NBLK  (BATCH / MB)    // 256 blocks -> 1 per CU (R14 experiment)
#define NTHR  256             // 4 waves, 1 wave/SIMD

typedef _Float16 half8 __attribute__((ext_vector_type(8)));
typedef float    f32x4 __attribute__((ext_vector_type(4)));

#define L2E 1.4426950408889634f
#define HSTRIDE 80            // 160 B rows: A-frag b128 reads land 2-way/free
                              // (R10/R12: conflicts 4.28e6 -> 8.6e4 cycles)

// R14: dual-group ILP experiment. R13 evidence: rcp-fusion cut absolute VALU
// cycles 10% with ZERO time change -> not issue-bound; per-step fixed costs
// (4-wave barrier + LDS turnaround) dominate. This version amortizes them
// over 8 rows/block (2 groups of 4 in the same 4 waves, shared wfrag),
// 1 block/CU. Per-CU pipe load is IDENTICAL to the 2-block MB=4 version;
// only the fixed-cost-per-row halves. Diagnostic if it fails: VALUBusy<45%
// means 1-wave/SIMD latency nakedness beat the amortization.
// Kept from prior rounds: NO setprio (m190-class lockstep null), NO variable
// C-in fold (R13: allocator rematerializes, +13% VALU), rcp fusion (R13),
// persistent zero4 C-in, HSTRIDE=80.
__global__ __launch_bounds__(NTHR, 1) void lstm_kernel(
    const float* __restrict__ x,      // (S, BATCH)
    const float* __restrict__ W_ih,   // (256,1)
    const float* __restrict__ W_hh,   // (256,64)
    const float* __restrict__ b_ih,   // (256,)
    const float* __restrict__ b_hh,   // (256,)
    const float* __restrict__ fc1_w,  // (128,64)
    const float* __restrict__ fc1_b,  // (128,)
    const float* __restrict__ fc2_w,  // (5,128)
    const float* __restrict__ fc2_b,  // (5,)
    float* __restrict__ out)          // (BATCH,5)
{
    // x staged ONCE, TRANSPOSED to [b][s]: in-loop x becomes one b128 read
    // per 4 steps (register prefetch) instead of one b32 read per step.
    __shared__ __align__(16) float    xs_t[MB * S_LEN];               // 32 KB
    __shared__ __align__(16) _Float16 h_buf[2][2][GB * HSTRIDE];      // 2.5 KB
    __shared__ __align__(16) float    head_lds[MB * HID + MB * 128];  // 6 KB

    const int tid  = threadIdx.x;
    const int lane = tid & 63;
    const int wave = tid >> 6;        // 0..3
    const int l15  = lane & 15;
    const int quad = lane >> 4;       // 0..3
    const int b0   = blockIdx.x * MB;

    // ---- stage x with transpose: global (S,B) slice -> xs_t[b][s] ----
    for (int i = tid; i < S_LEN * 2; i += NTHR) {
        const int s = i >> 1, hh = (i & 1) * 4;
        const float4 v = *(const float4*)(x + (size_t)s * BATCH + b0 + hh);
        xs_t[(hh + 0) * S_LEN + s] = v.x;
        xs_t[(hh + 1) * S_LEN + s] = v.y;
        xs_t[(hh + 2) * S_LEN + s] = v.z;
        xs_t[(hh + 3) * S_LEN + s] = v.w;
    }

    // ---- zero all four h buffers (h0 = 0): 2560 B = 640 dwords ----
    {
        unsigned* hz = (unsigned*)&h_buf[0][0][0];
        for (int i = tid; i < 2 * 2 * GB * HSTRIDE / 2; i += NTHR) hz[i] = 0u;
    }

    // ---- stationary W_hh B-fragments, per-wave unit slice (32 VGPRs) ----
    // SHARED by both groups (same weights). wave w, gate g: col n=l15 <->
    // W_hh row g*64 + 16w + l15; k = quad*8+j, k-tile kt adds 32.
    // Pre-scaled by -log2e (sigmoid) / -2log2e (tanh on g gate).
    half8 wfrag[4][2];
    #pragma unroll
    for (int g = 0; g < 4; ++g) {
        const float sc = (g == 2) ? (-2.0f * L2E) : (-L2E);
        const float* wr = W_hh + (g * 64 + 16 * wave + l15) * HID + quad * 8;
        #pragma unroll
        for (int kt = 0; kt < 2; ++kt) {
            half8 f;
            #pragma unroll
            for (int j = 0; j < 8; ++j) f[j] = (_Float16)(wr[kt * 32 + j] * sc);
            wfrag[g][kt] = f;
        }
    }

    // ---- elementwise ownership: thread (quad,l15) -> u=16*wave+l15;
    //      group 0 batch = quad, group 1 batch = 4+quad ----
    const int u = 16 * wave + l15;
    float wih_s[4], bias_s[4];
    #pragma unroll
    for (int g = 0; g < 4; ++g) {
        const int n = g * 64 + u;
        const float sc = (g == 2) ? (-2.0f * L2E) : (-L2E);
        wih_s[g]  = W_ih[n] * sc;
        bias_s[g] = (b_ih[n] + b_hh[n]) * sc;
    }

    float c0 = 0.0f, c1 = 0.0f;
    const f32x4 zero4 = {0.f, 0.f, 0.f, 0.f};   // persistent C-operand regs

    // hoisted LDS pointers: ar[g][buf] for A-frag reads, hw[g][buf] for h write
    const _Float16* ar00 = &h_buf[0][0][0] + (l15 >> 2) * HSTRIDE + quad * 8;
    const _Float16* ar01 = &h_buf[0][1][0] + (l15 >> 2) * HSTRIDE + quad * 8;
    const _Float16* ar10 = &h_buf[1][0][0] + (l15 >> 2) * HSTRIDE + quad * 8;
    const _Float16* ar11 = &h_buf[1][1][0] + (l15 >> 2) * HSTRIDE + quad * 8;
    _Float16* hw00 = &h_buf[0][0][0] + quad * HSTRIDE + u;
    _Float16* hw01 = &h_buf[0][1][0] + quad * HSTRIDE + u;
    _Float16* hw10 = &h_buf[1][0][0] + quad * HSTRIDE + u;
    _Float16* hw11 = &h_buf[1][1][0] + quad * HSTRIDE + u;
    const float* xg0 = xs_t + quad * S_LEN;         // group 0: batch quad
    const float* xg1 = xs_t + (4 + quad) * S_LEN;   // group 1: batch 4+quad

    __syncthreads();   // x staged + h zeroed visible

    auto body = [&](const _Float16* ar0, const _Float16* ar1,
                    _Float16* hw0, _Float16* hw1,
                    float xv0, float xv1) {
        // ---- both groups' A-frags issued together (4x ds_read_b128) ----
        half8 a00 = *(const half8*)(ar0);          // G0 k 0..31
        half8 a01 = *(const half8*)(ar0 + 32);     // G0 k 32..63
        half8 a10 = *(const half8*)(ar1);          // G1 k 0..31
        half8 a11 = *(const half8*)(ar1 + 32);     // G1 k 32..63

        // ---- MFMA, replicated A rows: C[4q+r][l15] = gates[b][u] ----
        f32x4 acc0[4], acc1[4];
        #pragma unroll
        for (int g = 0; g < 4; ++g) {
            acc0[g] = __builtin_amdgcn_mfma_f32_16x16x32_f16(a00, wfrag[g][0], zero4, 0, 0, 0);
            acc0[g] = __builtin_amdgcn_mfma_f32_16x16x32_f16(a01, wfrag[g][1], acc0[g], 0, 0, 0);
        }
        #pragma unroll
        for (int g = 0; g < 4; ++g) {
            acc1[g] = __builtin_amdgcn_mfma_f32_16x16x32_f16(a10, wfrag[g][0], zero4, 0, 0, 0);
            acc1[g] = __builtin_amdgcn_mfma_f32_16x16x32_f16(a11, wfrag[g][1], acc1[g], 0, 0, 0);
        }

        // ---- G0 elementwise (overlaps G1 MFMA latency) ----
        {
            const float gi = acc0[0][0] + __builtin_fmaf(xv0, wih_s[0], bias_s[0]);
            const float gf = acc0[1][0] + __builtin_fmaf(xv0, wih_s[1], bias_s[1]);
            const float gg = acc0[2][0] + __builtin_fmaf(xv0, wih_s[2], bias_s[2]);
            const float go = acc0[3][0] + __builtin_fmaf(xv0, wih_s[3], bias_s[3]);

            const float eA = __builtin_amdgcn_exp2f(gi);
            const float eF = __builtin_amdgcn_exp2f(gf);
            const float eC = __builtin_amdgcn_exp2f(gg);
            const float eO = __builtin_amdgcn_exp2f(go);

            const float f_ = __builtin_amdgcn_rcpf(1.0f + eF);
            const float R1 = __builtin_amdgcn_rcpf((1.0f + eA) * (1.0f + eC));
            const float ig = __builtin_fmaf(-eC, R1, R1);

            c0 = __builtin_fmaf(f_, c0, ig);

            const float eT = __builtin_amdgcn_exp2f((-2.0f * L2E) * c0);
            const float R2 = __builtin_amdgcn_rcpf((1.0f + eO) * (1.0f + eT));
            const float h  = __builtin_fmaf(-eT, R2, R2);
            hw0[0] = (_Float16)h;
        }
        // ---- G1 elementwise ----
        {
            const float gi = acc1[0][0] + __builtin_fmaf(xv1, wih_s[0], bias_s[0]);
            const float gf = acc1[1][0] + __builtin_fmaf(xv1, wih_s[1], bias_s[1]);
            const float gg = acc1[2][0] + __builtin_fmaf(xv1, wih_s[2], bias_s[2]);
            const float go = acc1[3][0] + __builtin_fmaf(xv1, wih_s[3], bias_s[3]);

            const float eA = __builtin_amdgcn_exp2f(gi);
            const float eF = __builtin_amdgcn_exp2f(gf);
            const float eC = __builtin_amdgcn_exp2f(gg);
            const float eO = __builtin_amdgcn_exp2f(go);

            const float f_ = __builtin_amdgcn_rcpf(1.0f + eF);
            const float R1 = __builtin_amdgcn_rcpf((1.0f + eA) * (1.0f + eC));
            const float ig = __builtin_fmaf(-eC, R1, R1);

            c1 = __builtin_fmaf(f_, c1, ig);

            const float eT = __builtin_amdgcn_exp2f((-2.0f * L2E) * c1);
            const float R2 = __builtin_amdgcn_rcpf((1.0f + eO) * (1.0f + eT));
            const float h  = __builtin_fmaf(-eT, R2, R2);
            hw1[0] = (_Float16)h;
        }
        __syncthreads();   // one barrier per 8 rows (was per 4)
    };

    for (int s = 0; s < S_LEN; s += 4) {
        const float4 x0 = *(const float4*)(xg0 + s);   // 4 steps of x, G0
        const float4 x1 = *(const float4*)(xg1 + s);   // 4 steps of x, G1
        body(ar00, ar10, hw01, hw11, x0.x, x1.x);      // read buf0, write buf1
        body(ar01, ar11, hw00, hw10, x0.y, x1.y);      // read buf1, write buf0
        body(ar00, ar10, hw01, hw11, x0.z, x1.z);
        body(ar01, ar11, hw00, hw10, x0.w, x1.w);
    }

    // ---------- fused FC head on final cell states (no activation) ----------
    float* c_lds  = head_lds;             // MB*64 floats: [b][u]
    float* h1_lds = head_lds + MB * HID;  // MB*128 floats: [b][j]
    c_lds[quad * HID + u]       = c0;
    c_lds[(4 + quad) * HID + u] = c1;
    __syncthreads();

    for (int idx = tid; idx < MB * 128; idx += NTHR) {
        const int b = idx >> 7, j = idx & 127;
        const float* wrow = fc1_w + j * HID;
        const float* crow = c_lds + b * HID;
        float acc = fc1_b[j];
        #pragma unroll
        for (int k = 0; k < HID; k += 4)
            acc += crow[k] * wrow[k] + crow[k+1] * wrow[k+1]
                 + crow[k+2] * wrow[k+2] + crow[k+3] * wrow[k+3];
        h1_lds[idx] = acc;
    }
    __syncthreads();

    if (tid < MB * 5) {
        const int b = tid / 5, q = tid % 5;
        const float* wrow = fc2_w + q * 128;
        const float* hrow = h1_lds + b * 128;
        float acc = fc2_b[q];
        #pragma unroll 4
        for (int j = 0; j < 128; ++j) acc += hrow[j] * wrow[j];
        out[(b0 + b) * 5 + q] = acc;
    }
}

extern "C" void kernel_launch(void* const* d_in, const int* in_sizes, int n_in,
                              void* d_out, int out_size, void* d_ws, size_t ws_size,
                              hipStream_t stream) {
    const float* x     = (const float*)d_in[0];
    const float* W_ih  = (const float*)d_in[1];
    const float* W_hh  = (const float*)d_in[2];
    const float* b_ih  = (const float*)d_in[3];
    const float* b_hh  = (const float*)d_in[4];
    const float* fc1_w = (const float*)d_in[5];
    const float* fc1_b = (const float*)d_in[6];
    const float* fc2_w = (const float*)d_in[7];
    const float* fc2_b = (const float*)d_in[8];
    float* out = (float*)d_out;

    lstm_kernel<<<NBLK, NTHR, 0, stream>>>(x, W_ih, W_hh, b_ih, b_hh,
                                           fc1_w, fc1_b, fc2_w, fc2_b, out);
}